// Round 1
// baseline (283.508 us; speedup 1.0000x reference)
//
#include <hip/hip_runtime.h>

// Problem constants (from reference setup_inputs):
//   vol [B=2, C=16, D=96, H=96, W=96] f32
//   xyz_sample [2, 512, 3] f32
//   A [1024, 3, 3] f32
//   weight [6, 1024] f32
//   out [2, 16*512, 1024] f32  (flat: b*8388608 + (c*512+f)*1024 + k)

#define NB 2
#define NC 16
#define NS 96          // D = H = W = 96
#define FEATS 512
#define NK 1024

// ---------------------------------------------------------------------------
// Transpose [B,C,D,H,W] -> [B,D,H,W,C] (channel-last) for vectorized gathers.
// One block per (b,d,h) row: 96 w * 16 c = 1536 floats through LDS.
// ---------------------------------------------------------------------------
__global__ __launch_bounds__(256) void transpose_cl_kernel(
    const float* __restrict__ vol, float* __restrict__ volT) {
  int bid = blockIdx.x;            // 0 .. B*D*H-1
  int h = bid % NS;
  int t = bid / NS;
  int d = t % NS;
  int b = t / NS;

  __shared__ float sm[NS * 17];    // [w][c] with +1 pad (stride 17, conflict-free)
  int tid = threadIdx.x;

  // Load: coalesced over w for each c
  for (int idx = tid; idx < NC * NS; idx += 256) {
    int c = idx / NS;
    int w = idx % NS;
    size_t src = ((((size_t)b * NC + c) * NS + d) * NS + h) * NS + w;
    sm[w * 17 + c] = vol[src];
  }
  __syncthreads();

  // Store: coalesced over (w*16 + c)
  size_t dstbase = (((size_t)(b * NS + d) * NS + h) * NS) * NC;
  for (int idx = tid; idx < NC * NS; idx += 256) {
    int w = idx / NC;
    int c = idx % NC;
    volT[dstbase + idx] = sm[w * 17 + c];
  }
}

// ---------------------------------------------------------------------------
// Trilinear accumulate (zero padding, align_corners=False) for 16 channels.
// CL=true: vol is channel-last [B,D,H,W,C]; CL=false: original [B,C,D,H,W].
// ---------------------------------------------------------------------------
template <bool CL>
__device__ __forceinline__ void trilinear_acc(
    const float* __restrict__ vol, int b,
    float x, float y, float z, float sgn, float* acc) {
  float fx0 = floorf(x), fy0 = floorf(y), fz0 = floorf(z);
  int ix0 = (int)fx0, iy0 = (int)fy0, iz0 = (int)fz0;
  float tx = x - fx0, ty = y - fy0, tz = z - fz0;
  float wx[2] = {1.0f - tx, tx};
  float wy[2] = {1.0f - ty, ty};
  float wz[2] = {1.0f - tz, tz};

#pragma unroll
  for (int dz = 0; dz < 2; dz++) {
    int zc = iz0 + dz;
    if ((unsigned)zc >= (unsigned)NS) continue;
#pragma unroll
    for (int dy = 0; dy < 2; dy++) {
      int yc = iy0 + dy;
      if ((unsigned)yc >= (unsigned)NS) continue;
#pragma unroll
      for (int dx = 0; dx < 2; dx++) {
        int xc = ix0 + dx;
        if ((unsigned)xc >= (unsigned)NS) continue;
        float w = sgn * wz[dz] * wy[dy] * wx[dx];
        if (CL) {
          const float4* p = (const float4*)(
              vol + ((((size_t)(b * NS + zc) * NS + yc) * NS + xc) << 4));
          float4 v0 = p[0], v1 = p[1], v2 = p[2], v3 = p[3];
          acc[0]  += w * v0.x; acc[1]  += w * v0.y;
          acc[2]  += w * v0.z; acc[3]  += w * v0.w;
          acc[4]  += w * v1.x; acc[5]  += w * v1.y;
          acc[6]  += w * v1.z; acc[7]  += w * v1.w;
          acc[8]  += w * v2.x; acc[9]  += w * v2.y;
          acc[10] += w * v2.z; acc[11] += w * v2.w;
          acc[12] += w * v3.x; acc[13] += w * v3.y;
          acc[14] += w * v3.z; acc[15] += w * v3.w;
        } else {
          size_t base = (size_t)b * NC * NS * NS * NS +
                        (size_t)zc * NS * NS + (size_t)yc * NS + xc;
#pragma unroll
          for (int c = 0; c < NC; c++)
            acc[c] += w * vol[base + (size_t)c * (NS * NS * NS)];
        }
      }
    }
  }
}

// ---------------------------------------------------------------------------
// Main kernel: one block per (b, f) feature point; threads cover k.
// Coordinate mapping (verified against reference):
//   grid[...,0] = zf = xs[0] + off_row2  -> x (W axis)
//   grid[...,1] = yf = xs[1] + off_row1  -> y (H axis)
//   grid[...,2] = xf = xs[2] + off_row0  -> z (D axis)
//   coord = (g + 1)*48 - 0.5
// ---------------------------------------------------------------------------
template <bool CL>
__global__ __launch_bounds__(256) void sample_kernel(
    const float* __restrict__ vol,      // volT if CL, else original
    const float* __restrict__ xyz,      // [B, 512, 3]
    const float* __restrict__ A,        // [1024, 3, 3]
    const float* __restrict__ weight,   // [6, 1024]
    float* __restrict__ out) {
  int n = blockIdx.x;   // b*512 + f
  int b = n >> 9;
  int f = n & 511;

  // Block-uniform loads -> compiler emits scalar loads
  const float* An = A + (size_t)n * 9;
  float a00 = An[0], a01 = An[1], a02 = An[2];
  float a10 = An[3], a11 = An[4], a12 = An[5];
  float a20 = An[6], a21 = An[7], a22 = An[8];
  const float* Xn = xyz + (size_t)n * 3;
  float bx = (Xn[0] + 1.0f) * 48.0f - 0.5f;  // W-axis base uses xs[0]
  float by = (Xn[1] + 1.0f) * 48.0f - 0.5f;  // H-axis base uses xs[1]
  float bz = (Xn[2] + 1.0f) * 48.0f - 0.5f;  // D-axis base uses xs[2]

  size_t obase = (size_t)b * (NC * FEATS * NK) + (size_t)f * NK;

  for (int k = threadIdx.x; k < NK; k += 256) {
    float w0 = weight[k];
    float w1 = weight[NK + k];
    float w2 = weight[2 * NK + k];
    float w3 = weight[3 * NK + k];
    float w4 = weight[4 * NK + k];
    float w5 = weight[5 * NK + k];

    float acc[NC];
#pragma unroll
    for (int c = 0; c < NC; c++) acc[c] = 0.0f;

    {  // grid 1 (weight rows 0..2), +1
      float o0 = a00 * w0 + a01 * w1 + a02 * w2;  // row0 -> z
      float o1 = a10 * w0 + a11 * w1 + a12 * w2;  // row1 -> y
      float o2 = a20 * w0 + a21 * w1 + a22 * w2;  // row2 -> x
      trilinear_acc<CL>(vol, b, bx + o2 * 48.0f, by + o1 * 48.0f,
                        bz + o0 * 48.0f, 1.0f, acc);
    }
    {  // grid 2 (weight rows 3..5), -1
      float o0 = a00 * w3 + a01 * w4 + a02 * w5;
      float o1 = a10 * w3 + a11 * w4 + a12 * w5;
      float o2 = a20 * w3 + a21 * w4 + a22 * w5;
      trilinear_acc<CL>(vol, b, bx + o2 * 48.0f, by + o1 * 48.0f,
                        bz + o0 * 48.0f, -1.0f, acc);
    }

#pragma unroll
    for (int c = 0; c < NC; c++)
      out[obase + (size_t)c * (FEATS * NK) + k] = acc[c];
  }
}

extern "C" void kernel_launch(void* const* d_in, const int* in_sizes, int n_in,
                              void* d_out, int out_size, void* d_ws,
                              size_t ws_size, hipStream_t stream) {
  const float* vol    = (const float*)d_in[0];
  const float* xyz    = (const float*)d_in[1];
  const float* A      = (const float*)d_in[2];
  const float* weight = (const float*)d_in[3];
  float* out = (float*)d_out;

  const size_t volT_bytes = (size_t)NB * NC * NS * NS * NS * sizeof(float);

  if (ws_size >= volT_bytes) {
    float* volT = (float*)d_ws;
    transpose_cl_kernel<<<NB * NS * NS, 256, 0, stream>>>(vol, volT);
    sample_kernel<true><<<NB * FEATS, 256, 0, stream>>>(volT, xyz, A, weight, out);
  } else {
    sample_kernel<false><<<NB * FEATS, 256, 0, stream>>>(vol, xyz, A, weight, out);
  }
}

// Round 2
// 260.224 us; speedup vs baseline: 1.0895x; 1.0895x over previous
//
#include <hip/hip_runtime.h>

// Problem constants:
//   vol [B=2, C=16, D=96, H=96, W=96] f32
//   xyz_sample [2, 512, 3] f32
//   A [1024, 3, 3] f32
//   weight [6, 1024] f32
//   out [2, 16*512, 1024] f32  (flat: b*8388608 + (c*512+f)*1024 + k)

#define NB 2
#define NC 16
#define NS 96
#define FEATS 512
#define NK 1024
#define KSPLIT 4            // k-segments per feature point -> grid 4096
#define KSHIFT 2
#define KCHUNK (NK / KSPLIT)   // 256
#define PASSES (KCHUNK / 64)   // 4 (64 k-values per pass: 4 lanes each)

// ---------------------------------------------------------------------------
// Transpose [B,C,D,H,W] -> [B,D,H,W,C] (channel-last).
// ---------------------------------------------------------------------------
__global__ __launch_bounds__(256) void transpose_cl_kernel(
    const float* __restrict__ vol, float* __restrict__ volT) {
  int bid = blockIdx.x;            // 0 .. B*D*H-1
  int h = bid % NS;
  int t = bid / NS;
  int d = t % NS;
  int b = t / NS;

  __shared__ float sm[NS * 17];
  int tid = threadIdx.x;

  for (int idx = tid; idx < NC * NS; idx += 256) {
    int c = idx / NS;
    int w = idx % NS;
    size_t src = ((((size_t)b * NC + c) * NS + d) * NS + h) * NS + w;
    sm[w * 17 + c] = vol[src];
  }
  __syncthreads();

  size_t dstbase = (((size_t)(b * NS + d) * NS + h) * NS) * NC;
  for (int idx = tid; idx < NC * NS; idx += 256) {
    int w = idx / NC;
    int c = idx % NC;
    volT[dstbase + idx] = sm[w * 17 + c];
  }
}

// ---------------------------------------------------------------------------
// Quad-split trilinear: each lane loads ONE float4 (its 4-channel slice) per
// corner. 4 lanes cover a sample's 64 B corner block in a single instruction.
// ---------------------------------------------------------------------------
__device__ __forceinline__ void tri_q(const float* __restrict__ vq,
                                      size_t bbase, float x, float y, float z,
                                      float sgn, float acc[4]) {
  float fx0 = floorf(x), fy0 = floorf(y), fz0 = floorf(z);
  int ix0 = (int)fx0, iy0 = (int)fy0, iz0 = (int)fz0;
  float tx = x - fx0, ty = y - fy0, tz = z - fz0;
  float wxa[2] = {1.0f - tx, tx};
  float wya[2] = {1.0f - ty, ty};
  float wza[2] = {1.0f - tz, tz};

#pragma unroll
  for (int dz = 0; dz < 2; dz++) {
    int zc = iz0 + dz;
    if ((unsigned)zc >= (unsigned)NS) continue;
#pragma unroll
    for (int dy = 0; dy < 2; dy++) {
      int yc = iy0 + dy;
      if ((unsigned)yc >= (unsigned)NS) continue;
      size_t rowb = bbase + ((size_t)zc * NS + yc) * (NS * NC);
      float wzy = sgn * wza[dz] * wya[dy];
#pragma unroll
      for (int dx = 0; dx < 2; dx++) {
        int xc = ix0 + dx;
        if ((unsigned)xc >= (unsigned)NS) continue;
        float w = wzy * wxa[dx];
        const float4 v = *(const float4*)(vq + rowb + (size_t)xc * NC);
        acc[0] += w * v.x;
        acc[1] += w * v.y;
        acc[2] += w * v.z;
        acc[3] += w * v.w;
      }
    }
  }
}

// ---------------------------------------------------------------------------
// Main kernel: grid = B*FEATS*KSPLIT blocks. Lane layout: quad = tid&3 picks
// the 4-channel slice, tid>>2 picks k within the pass (64 k / pass).
// ---------------------------------------------------------------------------
__global__ __launch_bounds__(256) void sample_kernel_q(
    const float* __restrict__ volT,     // [B,D,H,W,C]
    const float* __restrict__ xyz,      // [B, 512, 3]
    const float* __restrict__ A,        // [1024, 3, 3]
    const float* __restrict__ weight,   // [6, 1024]
    float* __restrict__ out) {
  __shared__ float wsm[6 * KCHUNK];     // 6 KB weight slice

  int bid = blockIdx.x;
  int kseg = bid & (KSPLIT - 1);
  int n = bid >> KSHIFT;                // b*512 + f
  int b = n >> 9;
  int f = n & 511;
  int kbase = kseg * KCHUNK;

  for (int i = threadIdx.x; i < 6 * KCHUNK; i += 256)
    wsm[i] = weight[(i / KCHUNK) * NK + kbase + (i % KCHUNK)];

  const float* An = A + (size_t)n * 9;
  float a00 = An[0], a01 = An[1], a02 = An[2];
  float a10 = An[3], a11 = An[4], a12 = An[5];
  float a20 = An[6], a21 = An[7], a22 = An[8];
  const float* Xn = xyz + (size_t)n * 3;
  float bx = (Xn[0] + 1.0f) * 48.0f - 0.5f;  // W axis <- xs[0]
  float by = (Xn[1] + 1.0f) * 48.0f - 0.5f;  // H axis <- xs[1]
  float bz = (Xn[2] + 1.0f) * 48.0f - 0.5f;  // D axis <- xs[2]
  __syncthreads();

  int quad = threadIdx.x & 3;
  int ksub = threadIdx.x >> 2;          // 0..63
  const float* vq = volT + quad * 4;    // this lane's channel slice
  size_t bbase = (size_t)b * (NS * NS * NS * NC);
  size_t obase = (size_t)b * (NC * FEATS * NK) +
                 (size_t)(quad * 4) * (FEATS * NK) + (size_t)f * NK + kbase;

  for (int pass = 0; pass < PASSES; pass++) {
    int kl = pass * 64 + ksub;          // local k within chunk
    float w0 = wsm[kl];
    float w1 = wsm[KCHUNK + kl];
    float w2 = wsm[2 * KCHUNK + kl];
    float w3 = wsm[3 * KCHUNK + kl];
    float w4 = wsm[4 * KCHUNK + kl];
    float w5 = wsm[5 * KCHUNK + kl];

    float acc[4] = {0.0f, 0.0f, 0.0f, 0.0f};

    {  // grid 1 (+)
      float oz = a00 * w0 + a01 * w1 + a02 * w2;  // row0 -> D axis
      float oy = a10 * w0 + a11 * w1 + a12 * w2;  // row1 -> H axis
      float ox = a20 * w0 + a21 * w1 + a22 * w2;  // row2 -> W axis
      tri_q(vq, bbase, bx + ox * 48.0f, by + oy * 48.0f, bz + oz * 48.0f,
            1.0f, acc);
    }
    {  // grid 2 (-)
      float oz = a00 * w3 + a01 * w4 + a02 * w5;
      float oy = a10 * w3 + a11 * w4 + a12 * w5;
      float ox = a20 * w3 + a21 * w4 + a22 * w5;
      tri_q(vq, bbase, bx + ox * 48.0f, by + oy * 48.0f, bz + oz * 48.0f,
            -1.0f, acc);
    }

    size_t o = obase + kl;
    out[o] = acc[0];
    out[o + (size_t)(FEATS * NK)] = acc[1];
    out[o + 2 * (size_t)(FEATS * NK)] = acc[2];
    out[o + 3 * (size_t)(FEATS * NK)] = acc[3];
  }
}

// ---------------------------------------------------------------------------
// Fallback (no workspace): original scalar-gather path, one block per (b,f).
// ---------------------------------------------------------------------------
__global__ __launch_bounds__(256) void sample_kernel_fallback(
    const float* __restrict__ vol, const float* __restrict__ xyz,
    const float* __restrict__ A, const float* __restrict__ weight,
    float* __restrict__ out) {
  int n = blockIdx.x;
  int b = n >> 9;
  int f = n & 511;
  const float* An = A + (size_t)n * 9;
  float a00 = An[0], a01 = An[1], a02 = An[2];
  float a10 = An[3], a11 = An[4], a12 = An[5];
  float a20 = An[6], a21 = An[7], a22 = An[8];
  const float* Xn = xyz + (size_t)n * 3;
  float bx = (Xn[0] + 1.0f) * 48.0f - 0.5f;
  float by = (Xn[1] + 1.0f) * 48.0f - 0.5f;
  float bz = (Xn[2] + 1.0f) * 48.0f - 0.5f;
  size_t obase = (size_t)b * (NC * FEATS * NK) + (size_t)f * NK;

  for (int k = threadIdx.x; k < NK; k += 256) {
    float w0 = weight[k], w1 = weight[NK + k], w2 = weight[2 * NK + k];
    float w3 = weight[3 * NK + k], w4 = weight[4 * NK + k],
          w5 = weight[5 * NK + k];
    float acc[NC];
#pragma unroll
    for (int c = 0; c < NC; c++) acc[c] = 0.0f;
    for (int g = 0; g < 2; g++) {
      float u0 = g ? w3 : w0, u1 = g ? w4 : w1, u2 = g ? w5 : w2;
      float sgn = g ? -1.0f : 1.0f;
      float oz = a00 * u0 + a01 * u1 + a02 * u2;
      float oy = a10 * u0 + a11 * u1 + a12 * u2;
      float ox = a20 * u0 + a21 * u1 + a22 * u2;
      float x = bx + ox * 48.0f, y = by + oy * 48.0f, z = bz + oz * 48.0f;
      float fx0 = floorf(x), fy0 = floorf(y), fz0 = floorf(z);
      int ix0 = (int)fx0, iy0 = (int)fy0, iz0 = (int)fz0;
      float tx = x - fx0, ty = y - fy0, tz = z - fz0;
      float wxa[2] = {1.0f - tx, tx}, wya[2] = {1.0f - ty, ty},
            wza[2] = {1.0f - tz, tz};
      for (int dz = 0; dz < 2; dz++) {
        int zc = iz0 + dz;
        if ((unsigned)zc >= (unsigned)NS) continue;
        for (int dy = 0; dy < 2; dy++) {
          int yc = iy0 + dy;
          if ((unsigned)yc >= (unsigned)NS) continue;
          for (int dx = 0; dx < 2; dx++) {
            int xc = ix0 + dx;
            if ((unsigned)xc >= (unsigned)NS) continue;
            float w = sgn * wza[dz] * wya[dy] * wxa[dx];
            size_t base = (size_t)b * NC * NS * NS * NS +
                          (size_t)zc * NS * NS + (size_t)yc * NS + xc;
#pragma unroll
            for (int c = 0; c < NC; c++)
              acc[c] += w * vol[base + (size_t)c * (NS * NS * NS)];
          }
        }
      }
    }
#pragma unroll
    for (int c = 0; c < NC; c++)
      out[obase + (size_t)c * (FEATS * NK) + k] = acc[c];
  }
}

extern "C" void kernel_launch(void* const* d_in, const int* in_sizes, int n_in,
                              void* d_out, int out_size, void* d_ws,
                              size_t ws_size, hipStream_t stream) {
  const float* vol    = (const float*)d_in[0];
  const float* xyz    = (const float*)d_in[1];
  const float* A      = (const float*)d_in[2];
  const float* weight = (const float*)d_in[3];
  float* out = (float*)d_out;

  const size_t volT_bytes = (size_t)NB * NC * NS * NS * NS * sizeof(float);

  if (ws_size >= volT_bytes) {
    float* volT = (float*)d_ws;
    transpose_cl_kernel<<<NB * NS * NS, 256, 0, stream>>>(vol, volT);
    sample_kernel_q<<<NB * FEATS * KSPLIT, 256, 0, stream>>>(volT, xyz, A,
                                                             weight, out);
  } else {
    sample_kernel_fallback<<<NB * FEATS, 256, 0, stream>>>(vol, xyz, A, weight,
                                                           out);
  }
}

// Round 3
// 242.674 us; speedup vs baseline: 1.1683x; 1.0723x over previous
//
#include <hip/hip_runtime.h>

// Problem constants:
//   vol [B=2, C=16, D=96, H=96, W=96] f32
//   xyz_sample [2, 512, 3] f32
//   A [1024, 3, 3] f32
//   weight [6, 1024] f32
//   out [2, 16*512, 1024] f32  (flat: b*8388608 + (c*512+f)*1024 + k)

#define NB 2
#define NC 16
#define NS 96
#define FEATS 512
#define NK 1024
#define KSPLIT 4
#define KSHIFT 2
#define KCHUNK (NK / KSPLIT)   // 256
#define PASSES (KCHUNK / 64)   // 4

#define TP 388   // LDS row stride (floats): %4==0 (b128-aligned), %32==4 (2-way only)

// ---------------------------------------------------------------------------
// Transpose + downconvert: [B,C,D,H,W] f32 -> [B,D,H,W,C] bf16.
// One block per (b, d, hq): 4 h-rows. float4 loads, b128 LDS, uint4 stores.
// ---------------------------------------------------------------------------
__device__ __forceinline__ unsigned int bfround(float f) {
  unsigned int u = __float_as_uint(f);
  return (u + 0x7fffu + ((u >> 16) & 1u)) >> 16;  // RNE
}

__global__ __launch_bounds__(256) void transpose_bf16_kernel(
    const float* __restrict__ vol, unsigned short* __restrict__ volT) {
  int bid = blockIdx.x;            // b*96*24 + d*24 + hq
  int hq = bid % 24;
  int t = bid / 24;
  int d = t % NS;
  int b = t / NS;

  __shared__ float sm[NC * TP];    // 24.8 KB
  int tid = threadIdx.x;

  // Load: 6 float4/thread, contiguous over the (h,w) plane per channel.
  const float4* v4 = (const float4*)vol;
#pragma unroll
  for (int j = 0; j < 6; j++) {
    int i = tid + 256 * j;         // 0..1535
    int c = i / 96;
    int u = i - c * 96;            // float4 index within the 4-row chunk
    size_t src = (size_t)((b * NC + c) * NS + d) * 2304 + hq * 96 + u;
    *(float4*)&sm[c * TP + u * 4] = v4[src];
  }
  __syncthreads();

  // Store: 3 x 16B chunks/thread. Chunk m: t16 = h_local*96+w, ch = c-half.
  size_t dstb = ((size_t)(b * NS + d) * 9216 + (size_t)hq * 384) * NC;  // ushort idx
#pragma unroll
  for (int j = 0; j < 3; j++) {
    int m = tid + 256 * j;         // 0..767
    int t16 = m >> 1;
    int ch = m & 1;
    unsigned int r[4];
#pragma unroll
    for (int q = 0; q < 4; q++) {
      float lo = sm[(ch * 8 + 2 * q) * TP + t16];
      float hi = sm[(ch * 8 + 2 * q + 1) * TP + t16];
      r[q] = bfround(lo) | (bfround(hi) << 16);
    }
    *(uint4*)(volT + dstb + (size_t)m * 8) = make_uint4(r[0], r[1], r[2], r[3]);
  }
}

// ---------------------------------------------------------------------------
// Quad-split trilinear over bf16 channel-last volume. Each lane loads its
// 4-channel slice (8 B uint2) per corner; 4 lanes cover a sample.
// ---------------------------------------------------------------------------
__device__ __forceinline__ void tri_q_bf16(const unsigned short* __restrict__ vq,
                                           size_t bbase, float x, float y,
                                           float z, float sgn, float acc[4]) {
  float fx0 = floorf(x), fy0 = floorf(y), fz0 = floorf(z);
  int ix0 = (int)fx0, iy0 = (int)fy0, iz0 = (int)fz0;
  float tx = x - fx0, ty = y - fy0, tz = z - fz0;
  float wxa[2] = {1.0f - tx, tx};
  float wya[2] = {1.0f - ty, ty};
  float wza[2] = {1.0f - tz, tz};

#pragma unroll
  for (int dz = 0; dz < 2; dz++) {
    int zc = iz0 + dz;
    if ((unsigned)zc >= (unsigned)NS) continue;
#pragma unroll
    for (int dy = 0; dy < 2; dy++) {
      int yc = iy0 + dy;
      if ((unsigned)yc >= (unsigned)NS) continue;
      size_t rowb = bbase + ((size_t)zc * NS + yc) * (NS * NC);
      float wzy = sgn * wza[dz] * wya[dy];
#pragma unroll
      for (int dx = 0; dx < 2; dx++) {
        int xc = ix0 + dx;
        if ((unsigned)xc >= (unsigned)NS) continue;
        float w = wzy * wxa[dx];
        uint2 u = *(const uint2*)(vq + rowb + (size_t)xc * NC);
        acc[0] += w * __uint_as_float(u.x << 16);
        acc[1] += w * __uint_as_float(u.x & 0xffff0000u);
        acc[2] += w * __uint_as_float(u.y << 16);
        acc[3] += w * __uint_as_float(u.y & 0xffff0000u);
      }
    }
  }
}

__global__ __launch_bounds__(256) void sample_kernel_q(
    const unsigned short* __restrict__ volT,  // [B,D,H,W,C] bf16
    const float* __restrict__ xyz, const float* __restrict__ A,
    const float* __restrict__ weight, float* __restrict__ out) {
  __shared__ float wsm[6 * KCHUNK];

  int bid = blockIdx.x;
  int kseg = bid & (KSPLIT - 1);
  int n = bid >> KSHIFT;                // b*512 + f
  int b = n >> 9;
  int f = n & 511;
  int kbase = kseg * KCHUNK;

  for (int i = threadIdx.x; i < 6 * KCHUNK; i += 256)
    wsm[i] = weight[(i / KCHUNK) * NK + kbase + (i % KCHUNK)];

  const float* An = A + (size_t)n * 9;
  float a00 = An[0], a01 = An[1], a02 = An[2];
  float a10 = An[3], a11 = An[4], a12 = An[5];
  float a20 = An[6], a21 = An[7], a22 = An[8];
  const float* Xn = xyz + (size_t)n * 3;
  float bx = (Xn[0] + 1.0f) * 48.0f - 0.5f;  // W axis <- xs[0]
  float by = (Xn[1] + 1.0f) * 48.0f - 0.5f;  // H axis <- xs[1]
  float bz = (Xn[2] + 1.0f) * 48.0f - 0.5f;  // D axis <- xs[2]
  __syncthreads();

  int quad = threadIdx.x & 3;
  int ksub = threadIdx.x >> 2;          // 0..63
  const unsigned short* vq = volT + quad * 4;
  size_t bbase = (size_t)b * (NS * NS * NS * NC);
  size_t obase = (size_t)b * (NC * FEATS * NK) +
                 (size_t)(quad * 4) * (FEATS * NK) + (size_t)f * NK + kbase;

  for (int pass = 0; pass < PASSES; pass++) {
    int kl = pass * 64 + ksub;
    float w0 = wsm[kl];
    float w1 = wsm[KCHUNK + kl];
    float w2 = wsm[2 * KCHUNK + kl];
    float w3 = wsm[3 * KCHUNK + kl];
    float w4 = wsm[4 * KCHUNK + kl];
    float w5 = wsm[5 * KCHUNK + kl];

    float acc[4] = {0.0f, 0.0f, 0.0f, 0.0f};

    {  // grid 1 (+)
      float oz = a00 * w0 + a01 * w1 + a02 * w2;
      float oy = a10 * w0 + a11 * w1 + a12 * w2;
      float ox = a20 * w0 + a21 * w1 + a22 * w2;
      tri_q_bf16(vq, bbase, bx + ox * 48.0f, by + oy * 48.0f, bz + oz * 48.0f,
                 1.0f, acc);
    }
    {  // grid 2 (-)
      float oz = a00 * w3 + a01 * w4 + a02 * w5;
      float oy = a10 * w3 + a11 * w4 + a12 * w5;
      float ox = a20 * w3 + a21 * w4 + a22 * w5;
      tri_q_bf16(vq, bbase, bx + ox * 48.0f, by + oy * 48.0f, bz + oz * 48.0f,
                 -1.0f, acc);
    }

    size_t o = obase + kl;
    out[o] = acc[0];
    out[o + (size_t)(FEATS * NK)] = acc[1];
    out[o + 2 * (size_t)(FEATS * NK)] = acc[2];
    out[o + 3 * (size_t)(FEATS * NK)] = acc[3];
  }
}

// ---------------------------------------------------------------------------
// Fallback (no workspace): scalar-gather on original f32 layout.
// ---------------------------------------------------------------------------
__global__ __launch_bounds__(256) void sample_kernel_fallback(
    const float* __restrict__ vol, const float* __restrict__ xyz,
    const float* __restrict__ A, const float* __restrict__ weight,
    float* __restrict__ out) {
  int n = blockIdx.x;
  int b = n >> 9;
  int f = n & 511;
  const float* An = A + (size_t)n * 9;
  float a00 = An[0], a01 = An[1], a02 = An[2];
  float a10 = An[3], a11 = An[4], a12 = An[5];
  float a20 = An[6], a21 = An[7], a22 = An[8];
  const float* Xn = xyz + (size_t)n * 3;
  float bx = (Xn[0] + 1.0f) * 48.0f - 0.5f;
  float by = (Xn[1] + 1.0f) * 48.0f - 0.5f;
  float bz = (Xn[2] + 1.0f) * 48.0f - 0.5f;
  size_t obase = (size_t)b * (NC * FEATS * NK) + (size_t)f * NK;

  for (int k = threadIdx.x; k < NK; k += 256) {
    float w0 = weight[k], w1 = weight[NK + k], w2 = weight[2 * NK + k];
    float w3 = weight[3 * NK + k], w4 = weight[4 * NK + k],
          w5 = weight[5 * NK + k];
    float acc[NC];
#pragma unroll
    for (int c = 0; c < NC; c++) acc[c] = 0.0f;
    for (int g = 0; g < 2; g++) {
      float u0 = g ? w3 : w0, u1 = g ? w4 : w1, u2 = g ? w5 : w2;
      float sgn = g ? -1.0f : 1.0f;
      float oz = a00 * u0 + a01 * u1 + a02 * u2;
      float oy = a10 * u0 + a11 * u1 + a12 * u2;
      float ox = a20 * u0 + a21 * u1 + a22 * u2;
      float x = bx + ox * 48.0f, y = by + oy * 48.0f, z = bz + oz * 48.0f;
      float fx0 = floorf(x), fy0 = floorf(y), fz0 = floorf(z);
      int ix0 = (int)fx0, iy0 = (int)fy0, iz0 = (int)fz0;
      float tx = x - fx0, ty = y - fy0, tz = z - fz0;
      float wxa[2] = {1.0f - tx, tx}, wya[2] = {1.0f - ty, ty},
            wza[2] = {1.0f - tz, tz};
      for (int dz = 0; dz < 2; dz++) {
        int zc = iz0 + dz;
        if ((unsigned)zc >= (unsigned)NS) continue;
        for (int dy = 0; dy < 2; dy++) {
          int yc = iy0 + dy;
          if ((unsigned)yc >= (unsigned)NS) continue;
          for (int dx = 0; dx < 2; dx++) {
            int xc = ix0 + dx;
            if ((unsigned)xc >= (unsigned)NS) continue;
            float w = sgn * wza[dz] * wya[dy] * wxa[dx];
            size_t base = (size_t)b * NC * NS * NS * NS +
                          (size_t)zc * NS * NS + (size_t)yc * NS + xc;
#pragma unroll
            for (int c = 0; c < NC; c++)
              acc[c] += w * vol[base + (size_t)c * (NS * NS * NS)];
          }
        }
      }
    }
#pragma unroll
    for (int c = 0; c < NC; c++)
      out[obase + (size_t)c * (FEATS * NK) + k] = acc[c];
  }
}

extern "C" void kernel_launch(void* const* d_in, const int* in_sizes, int n_in,
                              void* d_out, int out_size, void* d_ws,
                              size_t ws_size, hipStream_t stream) {
  const float* vol    = (const float*)d_in[0];
  const float* xyz    = (const float*)d_in[1];
  const float* A      = (const float*)d_in[2];
  const float* weight = (const float*)d_in[3];
  float* out = (float*)d_out;

  const size_t volT_bytes =
      (size_t)NB * NC * NS * NS * NS * sizeof(unsigned short);

  if (ws_size >= volT_bytes) {
    unsigned short* volT = (unsigned short*)d_ws;
    transpose_bf16_kernel<<<NB * NS * 24, 256, 0, stream>>>(vol, volT);
    sample_kernel_q<<<NB * FEATS * KSPLIT, 256, 0, stream>>>(volT, xyz, A,
                                                             weight, out);
  } else {
    sample_kernel_fallback<<<NB * FEATS, 256, 0, stream>>>(vol, xyz, A, weight,
                                                           out);
  }
}